// Round 2
// baseline (225.062 us; speedup 1.0000x reference)
//
#include <hip/hip_runtime.h>
#include <hip/hip_bf16.h>

#define S_LEN 2048
#define NH 16
#define DKH 64
#define DM 1024
// 1/sqrt(64) * log2(e): scores scaled into exp2 domain
#define QK_SCALE_L2E 0.1803368801111244f

typedef __attribute__((ext_vector_type(8))) short bf16x8;
typedef __attribute__((ext_vector_type(4))) float f32x4;
typedef __attribute__((ext_vector_type(4))) unsigned int u32x4;

__device__ __forceinline__ unsigned short f2bf(float f) {
  unsigned int x = __builtin_bit_cast(unsigned int, f);
  x += 0x7fffu + ((x >> 16) & 1u);   // RNE
  return (unsigned short)(x >> 16);
}

__device__ __forceinline__ void gload_lds16(const void* g, void* l) {
  __builtin_amdgcn_global_load_lds(
      (const __attribute__((address_space(1))) unsigned int*)g,
      (__attribute__((address_space(3))) unsigned int*)l, 16, 0, 0);
}

// ---------------- fp32 -> bf16 conversion (memory-bound pre-pass) -----------
__global__ void cvt_f32_to_bf16(const float* __restrict__ in,
                                unsigned short* __restrict__ out, int n) {
  int i = (blockIdx.x * blockDim.x + threadIdx.x) * 8;
  if (i >= n) return;
  float4 a = *(const float4*)(in + i);
  float4 b = *(const float4*)(in + i + 4);
  union { unsigned short us[8]; u32x4 v; } r;
  r.us[0] = f2bf(a.x); r.us[1] = f2bf(a.y); r.us[2] = f2bf(a.z); r.us[3] = f2bf(a.w);
  r.us[4] = f2bf(b.x); r.us[5] = f2bf(b.y); r.us[6] = f2bf(b.z); r.us[7] = f2bf(b.w);
  *(u32x4*)(out + i) = r.v;
}

// ---------------- 128x128 bf16 GEMM, C = A * B^T (m97 structure) ------------
template<int MODE>
__global__ __launch_bounds__(256) void gemm_bt(
    const unsigned short* __restrict__ A,   // [M,K] bf16 row-major
    const unsigned short* __restrict__ Bt,  // [N,K] bf16 row-major
    const float* __restrict__ bias,         // [N]
    float* __restrict__ Cf,                 // MODE 1
    unsigned short* __restrict__ qo,        // MODE 0
    unsigned short* __restrict__ ko,
    unsigned short* __restrict__ vto,
    int M, int N, int K)
{
  __shared__ __align__(16) char Asm[128 * 128];
  __shared__ __align__(16) char Bsm[128 * 128];
  int t = threadIdx.x;
  int lane = t & 63, wid = t >> 6;
  int wr = wid >> 1, wc = wid & 1;
  int m0 = blockIdx.y << 7, n0 = blockIdx.x << 7;
  int gi = lane >> 4, c0 = lane & 15;
  int rs = t >> 3, uP = t & 7;

  f32x4 acc[4][4];
#pragma unroll
  for (int i = 0; i < 4; ++i)
#pragma unroll
    for (int j = 0; j < 4; ++j) acc[i][j] = (f32x4){0.f, 0.f, 0.f, 0.f};

  for (int kt = 0; kt < K; kt += 64) {
#pragma unroll
    for (int it = 0; it < 4; ++it) {
      int r = rs + it * 32;
      int c8 = uP ^ (r & 7);
      gload_lds16(A  + ((size_t)(m0 + r) * K + kt + c8 * 8), Asm + r * 128 + uP * 16);
      gload_lds16(Bt + ((size_t)(n0 + r) * K + kt + c8 * 8), Bsm + r * 128 + uP * 16);
    }
    __syncthreads();
#pragma unroll
    for (int kk = 0; kk < 2; ++kk) {
      bf16x8 af[4], bfr[4];
      int uL = kk * 4 + gi;
#pragma unroll
      for (int i = 0; i < 4; ++i) {
        int ra = wr * 64 + i * 16 + c0;
        af[i] = *(const bf16x8*)(Asm + ra * 128 + ((uL ^ (ra & 7)) * 16));
        int rb = wc * 64 + i * 16 + c0;
        bfr[i] = *(const bf16x8*)(Bsm + rb * 128 + ((uL ^ (rb & 7)) * 16));
      }
#pragma unroll
      for (int i = 0; i < 4; ++i)
#pragma unroll
        for (int j = 0; j < 4; ++j)
          acc[i][j] = __builtin_amdgcn_mfma_f32_16x16x32_bf16(af[i], bfr[j], acc[i][j], 0, 0, 0);
    }
    __syncthreads();
  }

#pragma unroll
  for (int i = 0; i < 4; ++i) {
#pragma unroll
    for (int j = 0; j < 4; ++j) {
#pragma unroll
      for (int rI = 0; rI < 4; ++rI) {
        int m = m0 + wr * 64 + i * 16 + gi * 4 + rI;
        int n = n0 + wc * 64 + j * 16 + c0;
        float v = acc[i][j][rI] + bias[n];
        if (MODE == 1) {
          Cf[(size_t)m * N + n] = v;
        } else {
          int b = m >> 11, s = m & 2047;
          int which = n >> 10, w2 = n & 1023;
          int h = w2 >> 6, dk = w2 & 63;
          unsigned short bv = f2bf(v);
          size_t hoff = (size_t)(b * NH + h);
          if (which == 0)      qo[(hoff * S_LEN + s) * DKH + dk] = bv;
          else if (which == 1) ko[(hoff * S_LEN + s) * DKH + dk] = bv;
          else                 vto[(hoff * DKH + dk) * S_LEN + s] = bv;  // V transposed
        }
      }
    }
  }
}

// ---------------- flash attention, causal, 4 waves x 16 q-rows --------------
// LPT order (qt = 31 - blockIdx.x) + double-buffered KV staging with counted
// vmcnt barriers (T3/T4-min): next tile's global_load_lds stay in flight
// across the barrier.
__global__ __launch_bounds__(256) void attn_fwd(
    const unsigned short* __restrict__ Q,   // [BH, S, 64] bf16
    const unsigned short* __restrict__ Kb,  // [BH, S, 64] bf16
    const unsigned short* __restrict__ Vt,  // [BH, 64, S] bf16
    unsigned short* __restrict__ Out)       // [B*S, 1024] bf16
{
  __shared__ __align__(16) char kbuf[2][64 * 128];
  __shared__ __align__(16) char vbuf[2][64 * 128];
  __shared__ __align__(16) unsigned short pbuf[4][16][88];  // 176B rows
  int t = threadIdx.x;
  int lane = t & 63, wid = t >> 6;
  int gi = lane >> 4, c0 = lane & 15;
  int qt = 31 - blockIdx.x;          // LPT: biggest blocks dispatch first
  int bh = blockIdx.y;
  int q0 = qt << 6;
  const unsigned short* Qh = Q  + (size_t)bh * S_LEN * DKH;
  const unsigned short* Kh = Kb + (size_t)bh * S_LEN * DKH;
  const unsigned short* Vh = Vt + (size_t)bh * DKH * S_LEN;

  bf16x8 qf[2];
  {
    int qrow = q0 + wid * 16 + c0;
#pragma unroll
    for (int ks = 0; ks < 2; ++ks)
      qf[ks] = *(const bf16x8*)(Qh + (size_t)qrow * DKH + ks * 32 + gi * 8);
  }

  float mrow[4], lrow[4];
  f32x4 o[4];
#pragma unroll
  for (int i = 0; i < 4; ++i) { mrow[i] = -1e30f; lrow[i] = 0.f; o[i] = (f32x4){0, 0, 0, 0}; }

  int rs = t >> 3, uP = t & 7;
  int nt = qt + 1;

  // prologue: stage tile 0 into buf 0
  {
#pragma unroll
    for (int it = 0; it < 2; ++it) {
      int r = rs + it * 32;
      int c8 = uP ^ (r & 7);
      gload_lds16(Kh + ((size_t)r * DKH + c8 * 8), kbuf[0] + r * 128 + uP * 16);
      gload_lds16(Vh + ((size_t)r * S_LEN + c8 * 8), vbuf[0] + r * 128 + uP * 16);
    }
  }

  int cur = 0;
  for (int tile = 0; tile < nt; ++tile) {
    if (tile + 1 < nt) {
      // stage next tile into buf^1, then wait only for current tile's 4 loads
      int kv0 = (tile + 1) << 6;
      int nb = cur ^ 1;
#pragma unroll
      for (int it = 0; it < 2; ++it) {
        int r = rs + it * 32;
        int c8 = uP ^ (r & 7);
        gload_lds16(Kh + ((size_t)(kv0 + r) * DKH + c8 * 8), kbuf[nb] + r * 128 + uP * 16);
        gload_lds16(Vh + ((size_t)r * S_LEN + kv0 + c8 * 8), vbuf[nb] + r * 128 + uP * 16);
      }
      asm volatile("s_waitcnt vmcnt(4)\n\ts_barrier" ::: "memory");
    } else {
      asm volatile("s_waitcnt vmcnt(0)\n\ts_barrier" ::: "memory");
    }

    // S = Q K^T (scaled into exp2 domain)
    f32x4 sc[4];
#pragma unroll
    for (int f = 0; f < 4; ++f) {
      f32x4 s = (f32x4){0, 0, 0, 0};
#pragma unroll
      for (int ks = 0; ks < 2; ++ks) {
        int rb = f * 16 + c0;
        int uL = ks * 4 + gi;
        bf16x8 kf = *(const bf16x8*)(kbuf[cur] + rb * 128 + ((uL ^ (rb & 7)) * 16));
        s = __builtin_amdgcn_mfma_f32_16x16x32_bf16(qf[ks], kf, s, 0, 0, 0);
      }
      sc[f] = s;
    }

    float tmax[4] = {-1e30f, -1e30f, -1e30f, -1e30f};
    bool diag = (tile == qt);
#pragma unroll
    for (int f = 0; f < 4; ++f) {
#pragma unroll
      for (int i = 0; i < 4; ++i) {
        float v = sc[f][i] * QK_SCALE_L2E;
        if (diag && (f * 16 + c0 > wid * 16 + gi * 4 + i)) v = -1e30f;
        sc[f][i] = v;
        tmax[i] = fmaxf(tmax[i], v);
      }
    }
#pragma unroll
    for (int i = 0; i < 4; ++i) {
      float v = tmax[i];
      v = fmaxf(v, __shfl_xor(v, 1));
      v = fmaxf(v, __shfl_xor(v, 2));
      v = fmaxf(v, __shfl_xor(v, 4));
      v = fmaxf(v, __shfl_xor(v, 8));
      tmax[i] = v;
    }
    float alpha[4];
#pragma unroll
    for (int i = 0; i < 4; ++i) {
      float mnew = fmaxf(mrow[i], tmax[i]);
      alpha[i] = exp2f(mrow[i] - mnew);
      mrow[i] = mnew;
    }
    float psum[4] = {0, 0, 0, 0};
#pragma unroll
    for (int f = 0; f < 4; ++f)
#pragma unroll
      for (int i = 0; i < 4; ++i) {
        float p = exp2f(sc[f][i] - mrow[i]);
        sc[f][i] = p;
        psum[i] += p;
      }
#pragma unroll
    for (int i = 0; i < 4; ++i) {
      float v = psum[i];
      v += __shfl_xor(v, 1);
      v += __shfl_xor(v, 2);
      v += __shfl_xor(v, 4);
      v += __shfl_xor(v, 8);
      lrow[i] = lrow[i] * alpha[i] + v;
    }
#pragma unroll
    for (int df = 0; df < 4; ++df)
#pragma unroll
      for (int i = 0; i < 4; ++i) o[df][i] *= alpha[i];

    // P -> per-wave LDS (bf16), read back as PV A-fragments
    unsigned short (*pb)[88] = pbuf[wid];
#pragma unroll
    for (int f = 0; f < 4; ++f)
#pragma unroll
      for (int i = 0; i < 4; ++i)
        pb[gi * 4 + i][f * 16 + c0] = f2bf(sc[f][i]);
    asm volatile("s_waitcnt lgkmcnt(0)" ::: "memory");

#pragma unroll
    for (int ks = 0; ks < 2; ++ks) {
      bf16x8 pa = *(const bf16x8*)((const char*)pb + c0 * 176 + (ks * 4 + gi) * 16);
#pragma unroll
      for (int df = 0; df < 4; ++df) {
        int rv = df * 16 + c0;
        int uL = ks * 4 + gi;
        bf16x8 vf = *(const bf16x8*)(vbuf[cur] + rv * 128 + ((uL ^ (rv & 7)) * 16));
        o[df] = __builtin_amdgcn_mfma_f32_16x16x32_bf16(pa, vf, o[df], 0, 0, 0);
      }
    }
    // all waves done reading buf[cur] before next iteration overwrites it
    asm volatile("s_barrier" ::: "memory");
    cur ^= 1;
  }

  int b = bh >> 4, h = bh & 15;
#pragma unroll
  for (int i = 0; i < 4; ++i) {
    float rl = 1.0f / lrow[i];
    int row = q0 + wid * 16 + gi * 4 + i;
    size_t base = ((size_t)(b * S_LEN) + row) * DM + h * DKH;
#pragma unroll
    for (int df = 0; df < 4; ++df)
      Out[base + df * 16 + c0] = f2bf(o[df][i] * rl);
  }
}

// ----------------------------------------------------------------------------
extern "C" void kernel_launch(void* const* d_in, const int* in_sizes, int n_in,
                              void* d_out, int out_size, void* d_ws, size_t ws_size,
                              hipStream_t stream) {
  const float* x       = (const float*)d_in[0];
  const float* w_atten = (const float*)d_in[1];
  const float* b_atten = (const float*)d_in[2];
  const float* w_proj  = (const float*)d_in[3];
  const float* b_proj  = (const float*)d_in[4];
  float* out = (float*)d_out;
  char* ws = (char*)d_ws;

  unsigned short* x_bf  = (unsigned short*)(ws);
  unsigned short* wa_bf = (unsigned short*)(ws + ((size_t)8  << 20));
  unsigned short* wp_bf = (unsigned short*)(ws + ((size_t)14 << 20));
  unsigned short* q_bf  = (unsigned short*)(ws + ((size_t)16 << 20));
  unsigned short* k_bf  = (unsigned short*)(ws + ((size_t)24 << 20));
  unsigned short* vt_bf = (unsigned short*)(ws + ((size_t)32 << 20));
  unsigned short* at_bf = (unsigned short*)(ws + ((size_t)40 << 20));

  cvt_f32_to_bf16<<<2048, 256, 0, stream>>>(x, x_bf, 4194304);
  cvt_f32_to_bf16<<<1536, 256, 0, stream>>>(w_atten, wa_bf, 3145728);
  cvt_f32_to_bf16<<<512, 256, 0, stream>>>(w_proj, wp_bf, 1048576);

  gemm_bt<0><<<dim3(24, 32), 256, 0, stream>>>(x_bf, wa_bf, b_atten, nullptr,
                                               q_bf, k_bf, vt_bf, 4096, 3072, 1024);
  attn_fwd<<<dim3(32, 32), 256, 0, stream>>>(q_bf, k_bf, vt_bf, at_bf);
  gemm_bt<1><<<dim3(8, 32), 256, 0, stream>>>(at_bf, wp_bf, b_proj, out,
                                              nullptr, nullptr, nullptr, 4096, 1024, 1024);
}

// Round 3
// 190.224 us; speedup vs baseline: 1.1831x; 1.1831x over previous
//
#include <hip/hip_runtime.h>
#include <hip/hip_bf16.h>

#define S_LEN 2048
#define NH 16
#define DKH 64
#define DM 1024
// 1/sqrt(64) * log2(e): scores scaled into exp2 domain
#define QK_SCALE_L2E 0.1803368801111244f

typedef __attribute__((ext_vector_type(8))) short bf16x8;
typedef __attribute__((ext_vector_type(4))) float f32x4;
typedef __attribute__((ext_vector_type(4))) unsigned int u32x4;

__device__ __forceinline__ unsigned short f2bf(float f) {
  unsigned int x = __builtin_bit_cast(unsigned int, f);
  x += 0x7fffu + ((x >> 16) & 1u);   // RNE
  return (unsigned short)(x >> 16);
}
__device__ __forceinline__ float bf2f(unsigned short u) {
  unsigned int x = ((unsigned int)u) << 16;
  return __builtin_bit_cast(float, x);
}

__device__ __forceinline__ void gload_lds16(const void* g, void* l) {
  __builtin_amdgcn_global_load_lds(
      (const __attribute__((address_space(1))) unsigned int*)g,
      (__attribute__((address_space(3))) unsigned int*)l, 16, 0, 0);
}

// ---------------- fp32 -> bf16 conversion (memory-bound pre-pass) -----------
__global__ void cvt_f32_to_bf16(const float* __restrict__ in,
                                unsigned short* __restrict__ out, int n) {
  int i = (blockIdx.x * blockDim.x + threadIdx.x) * 8;
  if (i >= n) return;
  float4 a = *(const float4*)(in + i);
  float4 b = *(const float4*)(in + i + 4);
  union { unsigned short us[8]; u32x4 v; } r;
  r.us[0] = f2bf(a.x); r.us[1] = f2bf(a.y); r.us[2] = f2bf(a.z); r.us[3] = f2bf(a.w);
  r.us[4] = f2bf(b.x); r.us[5] = f2bf(b.y); r.us[6] = f2bf(b.z); r.us[7] = f2bf(b.w);
  *(u32x4*)(out + i) = r.v;
}

// ---------------- 128x128 bf16 GEMM, C = A * B^T (m97 structure) ------------
template<int MODE>
__global__ __launch_bounds__(256) void gemm_bt(
    const unsigned short* __restrict__ A,   // [M,K] bf16 row-major
    const unsigned short* __restrict__ Bt,  // [N,K] bf16 row-major
    const float* __restrict__ bias,         // [N]
    float* __restrict__ Cf,                 // MODE 1
    unsigned short* __restrict__ qo,        // MODE 0
    unsigned short* __restrict__ ko,
    unsigned short* __restrict__ vto,
    int M, int N, int K)
{
  __shared__ __align__(16) char Asm[128 * 128];
  __shared__ __align__(16) char Bsm[128 * 128];
  int t = threadIdx.x;
  int lane = t & 63, wid = t >> 6;
  int wr = wid >> 1, wc = wid & 1;
  int m0 = blockIdx.y << 7, n0 = blockIdx.x << 7;
  int gi = lane >> 4, c0 = lane & 15;
  int rs = t >> 3, uP = t & 7;

  f32x4 acc[4][4];
#pragma unroll
  for (int i = 0; i < 4; ++i)
#pragma unroll
    for (int j = 0; j < 4; ++j) acc[i][j] = (f32x4){0.f, 0.f, 0.f, 0.f};

  for (int kt = 0; kt < K; kt += 64) {
#pragma unroll
    for (int it = 0; it < 4; ++it) {
      int r = rs + it * 32;
      int c8 = uP ^ (r & 7);
      gload_lds16(A  + ((size_t)(m0 + r) * K + kt + c8 * 8), Asm + r * 128 + uP * 16);
      gload_lds16(Bt + ((size_t)(n0 + r) * K + kt + c8 * 8), Bsm + r * 128 + uP * 16);
    }
    __syncthreads();
#pragma unroll
    for (int kk = 0; kk < 2; ++kk) {
      bf16x8 af[4], bfr[4];
      int uL = kk * 4 + gi;
#pragma unroll
      for (int i = 0; i < 4; ++i) {
        int ra = wr * 64 + i * 16 + c0;
        af[i] = *(const bf16x8*)(Asm + ra * 128 + ((uL ^ (ra & 7)) * 16));
        int rb = wc * 64 + i * 16 + c0;
        bfr[i] = *(const bf16x8*)(Bsm + rb * 128 + ((uL ^ (rb & 7)) * 16));
      }
#pragma unroll
      for (int i = 0; i < 4; ++i)
#pragma unroll
        for (int j = 0; j < 4; ++j)
          acc[i][j] = __builtin_amdgcn_mfma_f32_16x16x32_bf16(af[i], bfr[j], acc[i][j], 0, 0, 0);
    }
    __syncthreads();
  }

#pragma unroll
  for (int i = 0; i < 4; ++i) {
#pragma unroll
    for (int j = 0; j < 4; ++j) {
#pragma unroll
      for (int rI = 0; rI < 4; ++rI) {
        int m = m0 + wr * 64 + i * 16 + gi * 4 + rI;
        int n = n0 + wc * 64 + j * 16 + c0;
        float v = acc[i][j][rI] + bias[n];
        if (MODE == 1) {
          Cf[(size_t)m * N + n] = v;
        } else {
          int b = m >> 11, s = m & 2047;
          int which = n >> 10, w2 = n & 1023;
          int h = w2 >> 6, dk = w2 & 63;
          unsigned short bv = f2bf(v);
          size_t hoff = (size_t)(b * NH + h);
          if (which == 0)      qo[(hoff * S_LEN + s) * DKH + dk] = bv;
          else if (which == 1) ko[(hoff * S_LEN + s) * DKH + dk] = bv;
          else                 vto[(hoff * DKH + dk) * S_LEN + s] = bv;  // V transposed
        }
      }
    }
  }
}

// ---------------- split-KV flash attention work table (LPT order) -----------
// item -> (qt, first kv tile, n tiles). Chunks of <=16 tiles; qt>=16 split
// into [0,16) + [16,qt]. Sorted descending by nt so long blocks dispatch
// first and short ones backfill.
struct WorkItem { unsigned char qt, t0, nt; };
__device__ __constant__ WorkItem g_items[48] = {
  {15,0,16},
  {16,0,16},{17,0,16},{18,0,16},{19,0,16},{20,0,16},{21,0,16},{22,0,16},{23,0,16},
  {24,0,16},{25,0,16},{26,0,16},{27,0,16},{28,0,16},{29,0,16},{30,0,16},{31,0,16},
  {31,16,16},
  {14,0,15},{30,16,15},
  {13,0,14},{29,16,14},
  {12,0,13},{28,16,13},
  {11,0,12},{27,16,12},
  {10,0,11},{26,16,11},
  { 9,0,10},{25,16,10},
  { 8,0, 9},{24,16, 9},
  { 7,0, 8},{23,16, 8},
  { 6,0, 7},{22,16, 7},
  { 5,0, 6},{21,16, 6},
  { 4,0, 5},{20,16, 5},
  { 3,0, 4},{19,16, 4},
  { 2,0, 3},{18,16, 3},
  { 1,0, 2},{17,16, 2},
  { 0,0, 1},{16,16, 1},
};

// ---------------- flash attention (partial), causal, 4 waves x 16 q-rows ----
// Writes unnormalized partial O (bf16) + per-row m,l (f32, exp2 domain).
__global__ __launch_bounds__(256) void attn_part(
    const unsigned short* __restrict__ Q,   // [BH, S, 64] bf16
    const unsigned short* __restrict__ Kb,  // [BH, S, 64] bf16
    const unsigned short* __restrict__ Vt,  // [BH, 64, S] bf16
    unsigned short* __restrict__ pO,        // [1536][64][64] bf16
    float* __restrict__ pm,                 // [1536][64]
    float* __restrict__ pl)                 // [1536][64]
{
  __shared__ __align__(16) char kbuf[64 * 128];
  __shared__ __align__(16) char vbuf[64 * 128];
  __shared__ __align__(16) unsigned short pbuf[4][16][88];
  int t = threadIdx.x;
  int lane = t & 63, wid = t >> 6;
  int gi = lane >> 4, c0 = lane & 15;
  WorkItem wi = g_items[blockIdx.x];
  int bh = blockIdx.y;
  int qt = wi.qt, tile0 = wi.t0, nt = wi.nt;
  int pid = bh * 48 + (tile0 ? (32 + qt - 16) : qt);
  int q0 = qt << 6;
  const unsigned short* Qh = Q  + (size_t)bh * S_LEN * DKH;
  const unsigned short* Kh = Kb + (size_t)bh * S_LEN * DKH;
  const unsigned short* Vh = Vt + (size_t)bh * DKH * S_LEN;

  bf16x8 qf[2];
  {
    int qrow = q0 + wid * 16 + c0;
#pragma unroll
    for (int ks = 0; ks < 2; ++ks)
      qf[ks] = *(const bf16x8*)(Qh + (size_t)qrow * DKH + ks * 32 + gi * 8);
  }

  float mrow[4], lrow[4];
  f32x4 o[4];
#pragma unroll
  for (int i = 0; i < 4; ++i) { mrow[i] = -1e30f; lrow[i] = 0.f; o[i] = (f32x4){0, 0, 0, 0}; }

  int rs = t >> 3, uP = t & 7;
  for (int tt = 0; tt < nt; ++tt) {
    int tile = tile0 + tt;
    int kv0 = tile << 6;
#pragma unroll
    for (int it = 0; it < 2; ++it) {
      int r = rs + it * 32;
      int c8 = uP ^ (r & 7);
      gload_lds16(Kh + ((size_t)(kv0 + r) * DKH + c8 * 8), kbuf + r * 128 + uP * 16);
      gload_lds16(Vh + ((size_t)r * S_LEN + kv0 + c8 * 8), vbuf + r * 128 + uP * 16);
    }
    __syncthreads();

    // S = Q K^T (scaled into exp2 domain)
    f32x4 sc[4];
#pragma unroll
    for (int f = 0; f < 4; ++f) {
      f32x4 s = (f32x4){0, 0, 0, 0};
#pragma unroll
      for (int ks = 0; ks < 2; ++ks) {
        int rb = f * 16 + c0;
        int uL = ks * 4 + gi;
        bf16x8 kf = *(const bf16x8*)(kbuf + rb * 128 + ((uL ^ (rb & 7)) * 16));
        s = __builtin_amdgcn_mfma_f32_16x16x32_bf16(qf[ks], kf, s, 0, 0, 0);
      }
      sc[f] = s;
    }

    float tmax[4] = {-1e30f, -1e30f, -1e30f, -1e30f};
    bool diag = (tile == qt);
#pragma unroll
    for (int f = 0; f < 4; ++f) {
#pragma unroll
      for (int i = 0; i < 4; ++i) {
        float v = sc[f][i] * QK_SCALE_L2E;
        if (diag && (f * 16 + c0 > wid * 16 + gi * 4 + i)) v = -1e30f;
        sc[f][i] = v;
        tmax[i] = fmaxf(tmax[i], v);
      }
    }
#pragma unroll
    for (int i = 0; i < 4; ++i) {
      float v = tmax[i];
      v = fmaxf(v, __shfl_xor(v, 1));
      v = fmaxf(v, __shfl_xor(v, 2));
      v = fmaxf(v, __shfl_xor(v, 4));
      v = fmaxf(v, __shfl_xor(v, 8));
      tmax[i] = v;
    }
    float alpha[4];
#pragma unroll
    for (int i = 0; i < 4; ++i) {
      float mnew = fmaxf(mrow[i], tmax[i]);
      alpha[i] = exp2f(mrow[i] - mnew);
      mrow[i] = mnew;
    }
    float psum[4] = {0, 0, 0, 0};
#pragma unroll
    for (int f = 0; f < 4; ++f)
#pragma unroll
      for (int i = 0; i < 4; ++i) {
        float p = exp2f(sc[f][i] - mrow[i]);
        sc[f][i] = p;
        psum[i] += p;
      }
#pragma unroll
    for (int i = 0; i < 4; ++i) {
      float v = psum[i];
      v += __shfl_xor(v, 1);
      v += __shfl_xor(v, 2);
      v += __shfl_xor(v, 4);
      v += __shfl_xor(v, 8);
      lrow[i] = lrow[i] * alpha[i] + v;
    }
#pragma unroll
    for (int df = 0; df < 4; ++df)
#pragma unroll
      for (int i = 0; i < 4; ++i) o[df][i] *= alpha[i];

    // P -> per-wave LDS (bf16), read back as PV A-fragments
    unsigned short (*pb)[88] = pbuf[wid];
#pragma unroll
    for (int f = 0; f < 4; ++f)
#pragma unroll
      for (int i = 0; i < 4; ++i)
        pb[gi * 4 + i][f * 16 + c0] = f2bf(sc[f][i]);
    asm volatile("s_waitcnt lgkmcnt(0)" ::: "memory");

#pragma unroll
    for (int ks = 0; ks < 2; ++ks) {
      bf16x8 pa = *(const bf16x8*)((const char*)pb + c0 * 176 + (ks * 4 + gi) * 16);
#pragma unroll
      for (int df = 0; df < 4; ++df) {
        int rv = df * 16 + c0;
        int uL = ks * 4 + gi;
        bf16x8 vf = *(const bf16x8*)(vbuf + rv * 128 + ((uL ^ (rv & 7)) * 16));
        o[df] = __builtin_amdgcn_mfma_f32_16x16x32_bf16(pa, vf, o[df], 0, 0, 0);
      }
    }
    __syncthreads();
  }

  // store UNNORMALIZED partial: O bf16 [64][64], m/l f32 per row
  unsigned short* po = pO + (size_t)pid * 4096;
#pragma unroll
  for (int i = 0; i < 4; ++i) {
    int r = wid * 16 + gi * 4 + i;
#pragma unroll
    for (int df = 0; df < 4; ++df)
      po[r * 64 + df * 16 + c0] = f2bf(o[df][i]);
    if (c0 == 0) {
      pm[pid * 64 + r] = mrow[i];
      pl[pid * 64 + r] = lrow[i];
    }
  }
}

// ---------------- combine partials -> attn output [B*S, 1024] bf16 ----------
__global__ __launch_bounds__(256) void attn_combine(
    const unsigned short* __restrict__ pO,
    const float* __restrict__ pm,
    const float* __restrict__ pl,
    unsigned short* __restrict__ Out)
{
  int qt = blockIdx.x, bh = blockIdx.y;
  int t = threadIdx.x;
  int r = t >> 2, cseg = (t & 3) * 16;
  int pid0 = bh * 48 + qt;
  bool two = (qt >= 16);
  int pid1 = bh * 48 + 32 + qt - 16;

  float m0 = pm[pid0 * 64 + r];
  float l0 = pl[pid0 * 64 + r];
  float M = m0, w0 = 1.f, w1 = 0.f, l = l0;
  if (two) {
    float m1 = pm[pid1 * 64 + r];
    float l1 = pl[pid1 * 64 + r];
    M = fmaxf(m0, m1);
    w0 = exp2f(m0 - M);
    w1 = exp2f(m1 - M);
    l = w0 * l0 + w1 * l1;
  }
  float rl = 1.0f / l;

  const unsigned short* o0 = pO + (size_t)pid0 * 4096 + r * 64 + cseg;
  const unsigned short* o1 = pO + (size_t)pid1 * 4096 + r * 64 + cseg;
  int b = bh >> 4, h = bh & 15;
  size_t base = ((size_t)(b * S_LEN) + (qt * 64 + r)) * DM + h * DKH + cseg;

  bf16x8 a0 = *(const bf16x8*)o0;
  bf16x8 a1 = *(const bf16x8*)(o0 + 8);
  unsigned short res[16];
  if (two) {
    bf16x8 b0 = *(const bf16x8*)o1;
    bf16x8 b1 = *(const bf16x8*)(o1 + 8);
#pragma unroll
    for (int j = 0; j < 8; ++j) {
      res[j]     = f2bf((w0 * bf2f((unsigned short)a0[j]) + w1 * bf2f((unsigned short)b0[j])) * rl);
      res[j + 8] = f2bf((w0 * bf2f((unsigned short)a1[j]) + w1 * bf2f((unsigned short)b1[j])) * rl);
    }
  } else {
#pragma unroll
    for (int j = 0; j < 8; ++j) {
      res[j]     = f2bf(bf2f((unsigned short)a0[j]) * rl);
      res[j + 8] = f2bf(bf2f((unsigned short)a1[j]) * rl);
    }
  }
  *(u32x4*)(Out + base)     = *(u32x4*)res;
  *(u32x4*)(Out + base + 8) = *(u32x4*)(res + 8);
}

// ----------------------------------------------------------------------------
extern "C" void kernel_launch(void* const* d_in, const int* in_sizes, int n_in,
                              void* d_out, int out_size, void* d_ws, size_t ws_size,
                              hipStream_t stream) {
  const float* x       = (const float*)d_in[0];
  const float* w_atten = (const float*)d_in[1];
  const float* b_atten = (const float*)d_in[2];
  const float* w_proj  = (const float*)d_in[3];
  const float* b_proj  = (const float*)d_in[4];
  float* out = (float*)d_out;
  char* ws = (char*)d_ws;

  // [0,8M) x_bf, [8M,14M) wa_bf -- dead after gemm0; partials overlay here.
  unsigned short* x_bf  = (unsigned short*)(ws);
  unsigned short* wa_bf = (unsigned short*)(ws + ((size_t)8  << 20));
  unsigned short* wp_bf = (unsigned short*)(ws + ((size_t)14 << 20));
  unsigned short* q_bf  = (unsigned short*)(ws + ((size_t)16 << 20));
  unsigned short* k_bf  = (unsigned short*)(ws + ((size_t)24 << 20));
  unsigned short* vt_bf = (unsigned short*)(ws + ((size_t)32 << 20));
  unsigned short* at_bf = (unsigned short*)(ws + ((size_t)40 << 20));
  // partial buffers overlay x_bf/wa_bf: 1536*8KB O + 2*384KB m/l = 13.4MB < 14MB
  unsigned short* pO = (unsigned short*)(ws);
  float* pm = (float*)(ws + 12582912);
  float* pl = (float*)(ws + 12976128);

  cvt_f32_to_bf16<<<2048, 256, 0, stream>>>(x, x_bf, 4194304);
  cvt_f32_to_bf16<<<1536, 256, 0, stream>>>(w_atten, wa_bf, 3145728);
  cvt_f32_to_bf16<<<512, 256, 0, stream>>>(w_proj, wp_bf, 1048576);

  gemm_bt<0><<<dim3(24, 32), 256, 0, stream>>>(x_bf, wa_bf, b_atten, nullptr,
                                               q_bf, k_bf, vt_bf, 4096, 3072, 1024);
  attn_part<<<dim3(48, 32), 256, 0, stream>>>(q_bf, k_bf, vt_bf, pO, pm, pl);
  attn_combine<<<dim3(32, 32), 256, 0, stream>>>(pO, pm, pl, at_bf);
  gemm_bt<1><<<dim3(8, 32), 256, 0, stream>>>(at_bf, wp_bf, b_proj, out,
                                              nullptr, nullptr, nullptr, 4096, 1024, 1024);
}

// Round 4
// 149.695 us; speedup vs baseline: 1.5035x; 1.2707x over previous
//
#include <hip/hip_runtime.h>
#include <hip/hip_bf16.h>

#define S_LEN 2048
#define NH 16
#define DKH 64
#define DM 1024
// 1/sqrt(64) * log2(e): folded into Q at the QKV-GEMM epilogue
#define QK_SCALE_L2E 0.1803368801111244f

typedef __attribute__((ext_vector_type(8))) short bf16x8;
typedef __attribute__((ext_vector_type(4))) float f32x4;
typedef __attribute__((ext_vector_type(4))) unsigned int u32x4;

__device__ __forceinline__ unsigned short f2bf(float f) {
  unsigned int x = __builtin_bit_cast(unsigned int, f);
  x += 0x7fffu + ((x >> 16) & 1u);   // RNE
  return (unsigned short)(x >> 16);
}
__device__ __forceinline__ float bf2f(unsigned short u) {
  unsigned int x = ((unsigned int)u) << 16;
  return __builtin_bit_cast(float, x);
}
// hardware exp2 (1 TRANS op; denorm-flush fine for softmax)
__device__ __forceinline__ float exp2a(float x) {
  float r; asm("v_exp_f32 %0, %1" : "=v"(r) : "v"(x)); return r;
}
// pack 2 fp32 -> 2 bf16 in one op: D.lo = a, D.hi = b
__device__ __forceinline__ unsigned int cvtpk(float a, float b) {
  unsigned int r; asm("v_cvt_pk_bf16_f32 %0, %1, %2" : "=v"(r) : "v"(a), "v"(b)); return r;
}

__device__ __forceinline__ void gload_lds16(const void* g, void* l) {
  __builtin_amdgcn_global_load_lds(
      (const __attribute__((address_space(1))) unsigned int*)g,
      (__attribute__((address_space(3))) unsigned int*)l, 16, 0, 0);
}

// ---------------- fp32 -> bf16 conversion (memory-bound pre-pass) -----------
__global__ void cvt_f32_to_bf16(const float* __restrict__ in,
                                unsigned short* __restrict__ out, int n) {
  int i = (blockIdx.x * blockDim.x + threadIdx.x) * 8;
  if (i >= n) return;
  float4 a = *(const float4*)(in + i);
  float4 b = *(const float4*)(in + i + 4);
  union { unsigned short us[8]; u32x4 v; } r;
  r.us[0] = f2bf(a.x); r.us[1] = f2bf(a.y); r.us[2] = f2bf(a.z); r.us[3] = f2bf(a.w);
  r.us[4] = f2bf(b.x); r.us[5] = f2bf(b.y); r.us[6] = f2bf(b.z); r.us[7] = f2bf(b.w);
  *(u32x4*)(out + i) = r.v;
}

// ---------------- 128x128 bf16 GEMM, C = A * B^T (m97 structure) ------------
template<int MODE>
__global__ __launch_bounds__(256) void gemm_bt(
    const unsigned short* __restrict__ A,   // [M,K] bf16 row-major
    const unsigned short* __restrict__ Bt,  // [N,K] bf16 row-major
    const float* __restrict__ bias,         // [N]
    float* __restrict__ Cf,                 // MODE 1
    unsigned short* __restrict__ qo,        // MODE 0
    unsigned short* __restrict__ ko,
    unsigned short* __restrict__ vto,
    int M, int N, int K)
{
  __shared__ __align__(16) char Asm[128 * 128];
  __shared__ __align__(16) char Bsm[128 * 128];
  int t = threadIdx.x;
  int lane = t & 63, wid = t >> 6;
  int wr = wid >> 1, wc = wid & 1;
  int m0 = blockIdx.y << 7, n0 = blockIdx.x << 7;
  int gi = lane >> 4, c0 = lane & 15;
  int rs = t >> 3, uP = t & 7;

  f32x4 acc[4][4];
#pragma unroll
  for (int i = 0; i < 4; ++i)
#pragma unroll
    for (int j = 0; j < 4; ++j) acc[i][j] = (f32x4){0.f, 0.f, 0.f, 0.f};

  for (int kt = 0; kt < K; kt += 64) {
#pragma unroll
    for (int it = 0; it < 4; ++it) {
      int r = rs + it * 32;
      int c8 = uP ^ (r & 7);
      gload_lds16(A  + ((size_t)(m0 + r) * K + kt + c8 * 8), Asm + r * 128 + uP * 16);
      gload_lds16(Bt + ((size_t)(n0 + r) * K + kt + c8 * 8), Bsm + r * 128 + uP * 16);
    }
    __syncthreads();
#pragma unroll
    for (int kk = 0; kk < 2; ++kk) {
      bf16x8 af[4], bfr[4];
      int uL = kk * 4 + gi;
#pragma unroll
      for (int i = 0; i < 4; ++i) {
        int ra = wr * 64 + i * 16 + c0;
        af[i] = *(const bf16x8*)(Asm + ra * 128 + ((uL ^ (ra & 7)) * 16));
        int rb = wc * 64 + i * 16 + c0;
        bfr[i] = *(const bf16x8*)(Bsm + rb * 128 + ((uL ^ (rb & 7)) * 16));
      }
#pragma unroll
      for (int i = 0; i < 4; ++i)
#pragma unroll
        for (int j = 0; j < 4; ++j)
          acc[i][j] = __builtin_amdgcn_mfma_f32_16x16x32_bf16(af[i], bfr[j], acc[i][j], 0, 0, 0);
    }
    __syncthreads();
  }

#pragma unroll
  for (int i = 0; i < 4; ++i) {
#pragma unroll
    for (int j = 0; j < 4; ++j) {
#pragma unroll
      for (int rI = 0; rI < 4; ++rI) {
        int m = m0 + wr * 64 + i * 16 + gi * 4 + rI;
        int n = n0 + wc * 64 + j * 16 + c0;
        float v = acc[i][j][rI] + bias[n];
        if (MODE == 1) {
          Cf[(size_t)m * N + n] = v;
        } else {
          int b = m >> 11, s = m & 2047;
          int which = n >> 10, w2 = n & 1023;
          int h = w2 >> 6, dk = w2 & 63;
          size_t hoff = (size_t)(b * NH + h);
          if (which == 0) {
            // fold softmax scale (incl. log2 e) into Q
            qo[(hoff * S_LEN + s) * DKH + dk] = f2bf(v * QK_SCALE_L2E);
          } else if (which == 1) {
            ko[(hoff * S_LEN + s) * DKH + dk] = f2bf(v);
          } else {
            vto[(hoff * DKH + dk) * S_LEN + s] = f2bf(v);  // V transposed
          }
        }
      }
    }
  }
}

// ---------------- split-KV flash attention work table (LPT order) -----------
struct WorkItem { unsigned char qt, t0, nt; };
__device__ __constant__ WorkItem g_items[48] = {
  {15,0,16},
  {16,0,16},{17,0,16},{18,0,16},{19,0,16},{20,0,16},{21,0,16},{22,0,16},{23,0,16},
  {24,0,16},{25,0,16},{26,0,16},{27,0,16},{28,0,16},{29,0,16},{30,0,16},{31,0,16},
  {31,16,16},
  {14,0,15},{30,16,15},
  {13,0,14},{29,16,14},
  {12,0,13},{28,16,13},
  {11,0,12},{27,16,12},
  {10,0,11},{26,16,11},
  { 9,0,10},{25,16,10},
  { 8,0, 9},{24,16, 9},
  { 7,0, 8},{23,16, 8},
  { 6,0, 7},{22,16, 7},
  { 5,0, 6},{21,16, 6},
  { 4,0, 5},{20,16, 5},
  { 3,0, 4},{19,16, 4},
  { 2,0, 3},{18,16, 3},
  { 1,0, 2},{17,16, 2},
  { 0,0, 1},{16,16, 1},
};

// ---------------- flash attention (partial), swapped-QK^T in-reg softmax ----
// S^T = mfma(K, Q): lane holds q = c0, kv = f*16 + gi*4 + i  (16 vals/lane).
// Row reduces: in-lane tree + 2 shfl_xor(16,32). PV layout unchanged.
__global__ __launch_bounds__(256) void attn_part(
    const unsigned short* __restrict__ Q,   // [BH, S, 64] bf16, pre-scaled
    const unsigned short* __restrict__ Kb,  // [BH, S, 64] bf16
    const unsigned short* __restrict__ Vt,  // [BH, 64, S] bf16
    unsigned short* __restrict__ pO,        // [1536][64][64] bf16
    float* __restrict__ pm,                 // [1536][64]
    float* __restrict__ pl)                 // [1536][64]
{
  __shared__ __align__(16) char kbuf[64 * 128];
  __shared__ __align__(16) char vbuf[2][64 * 128];
  __shared__ __align__(16) unsigned short pbuf[4][16][88];  // 176B rows
  int t = threadIdx.x;
  int lane = t & 63, wid = t >> 6;
  int gi = lane >> 4, c0 = lane & 15;
  WorkItem wi = g_items[blockIdx.x];
  int bh = blockIdx.y;
  int qt = wi.qt, tile0 = wi.t0, nt = wi.nt;
  int pid = bh * 48 + (tile0 ? (32 + qt - 16) : qt);
  int q0 = qt << 6;
  const unsigned short* Qh = Q  + (size_t)bh * S_LEN * DKH;
  const unsigned short* Kh = Kb + (size_t)bh * S_LEN * DKH;
  const unsigned short* Vh = Vt + (size_t)bh * DKH * S_LEN;

  bf16x8 qf[2];
  {
    int qrow = q0 + wid * 16 + c0;
#pragma unroll
    for (int ks = 0; ks < 2; ++ks)
      qf[ks] = *(const bf16x8*)(Qh + (size_t)qrow * DKH + ks * 32 + gi * 8);
  }

  float mrow = -1e30f, lrow = 0.f;
  f32x4 o[4];
#pragma unroll
  for (int i = 0; i < 4; ++i) o[i] = (f32x4){0, 0, 0, 0};

  int rs = t >> 3, uP = t & 7;
  int q_abs = q0 + wid * 16 + c0;

  // strength-reduced staging pointers (tiles are consecutive)
  int c8 = uP ^ (rs & 7);
  const unsigned short* kp0 = Kh + ((size_t)(tile0 * 64 + rs) * DKH) + c8 * 8;
  const unsigned short* kp1 = kp0 + 32 * DKH;
  const unsigned short* vp0 = Vh + (size_t)rs * S_LEN + tile0 * 64 + c8 * 8;
  const unsigned short* vp1 = vp0 + (size_t)32 * S_LEN;
  char* klds0 = kbuf + rs * 128 + uP * 16;
  char* klds1 = klds0 + 32 * 128;
  int vlds_off0 = rs * 128 + uP * 16;

  // prologue: stage tile0 -> kbuf, vbuf[0]
  gload_lds16(kp0, klds0);
  gload_lds16(kp1, klds1);
  gload_lds16(vp0, vbuf[0] + vlds_off0);
  gload_lds16(vp1, vbuf[0] + vlds_off0 + 32 * 128);
  kp0 += 64 * DKH; kp1 += 64 * DKH; vp0 += 64; vp1 += 64;

  for (int tt = 0; tt < nt; ++tt) {
    int tile = tile0 + tt;
    int kv0 = tile << 6;
    __syncthreads();   // staged K(t), V(t) landed (drains vmcnt+lgkm)

    // S^T = K * Q^T: sc[f][i] = S[q=c0][kv = kv0 + f*16 + gi*4 + i]
    f32x4 sc[4];
#pragma unroll
    for (int f = 0; f < 4; ++f) {
      f32x4 s = (f32x4){0, 0, 0, 0};
#pragma unroll
      for (int ks = 0; ks < 2; ++ks) {
        int rb = f * 16 + c0;
        int uL = ks * 4 + gi;
        bf16x8 kf = *(const bf16x8*)(kbuf + rb * 128 + ((uL ^ (rb & 7)) * 16));
        s = __builtin_amdgcn_mfma_f32_16x16x32_bf16(kf, qf[ks], s, 0, 0, 0);
      }
      sc[f] = s;
    }
    __syncthreads();   // all waves done reading kbuf

    // early-issue next tile's staging; lands during softmax+PV
    if (tt + 1 < nt) {
      char* vb = vbuf[(tt + 1) & 1];
      gload_lds16(kp0, klds0);
      gload_lds16(kp1, klds1);
      gload_lds16(vp0, vb + vlds_off0);
      gload_lds16(vp1, vb + vlds_off0 + 32 * 128);
      kp0 += 64 * DKH; kp1 += 64 * DKH; vp0 += 64; vp1 += 64;
    }

    // causal mask (diag tile only; uniform branch)
    if (tile == qt) {
      int kvb = kv0 + gi * 4;
#pragma unroll
      for (int f = 0; f < 4; ++f)
#pragma unroll
        for (int i = 0; i < 4; ++i)
          if (kvb + f * 16 + i > q_abs) sc[f][i] = -1e30f;
    }

    // in-lane max over 16, then reduce across gi lanes
    float m01 = fmaxf(fmaxf(sc[0][0], sc[0][1]), fmaxf(sc[0][2], sc[0][3]));
    float m23 = fmaxf(fmaxf(sc[1][0], sc[1][1]), fmaxf(sc[1][2], sc[1][3]));
    float m45 = fmaxf(fmaxf(sc[2][0], sc[2][1]), fmaxf(sc[2][2], sc[2][3]));
    float m67 = fmaxf(fmaxf(sc[3][0], sc[3][1]), fmaxf(sc[3][2], sc[3][3]));
    float tmax = fmaxf(fmaxf(m01, m23), fmaxf(m45, m67));
    tmax = fmaxf(tmax, __shfl_xor(tmax, 16));
    tmax = fmaxf(tmax, __shfl_xor(tmax, 32));

    float alpha = 1.f;
    if (__any(tmax > mrow)) {          // defer-max: skip rescale if no growth
      float mnew = fmaxf(mrow, tmax);
      alpha = exp2a(mrow - mnew);
      mrow = mnew;
      float af0 = __shfl(alpha, gi * 4 + 0);
      float af1 = __shfl(alpha, gi * 4 + 1);
      float af2 = __shfl(alpha, gi * 4 + 2);
      float af3 = __shfl(alpha, gi * 4 + 3);
#pragma unroll
      for (int df = 0; df < 4; ++df) {
        o[df][0] *= af0; o[df][1] *= af1; o[df][2] *= af2; o[df][3] *= af3;
      }
    }

    // P = exp2(S - m), in-lane partial sums (4 chains of depth 4)
    float ps0 = 0, ps1 = 0, ps2 = 0, ps3 = 0;
#pragma unroll
    for (int f = 0; f < 4; ++f) {
      float p0 = exp2a(sc[f][0] - mrow);
      float p1 = exp2a(sc[f][1] - mrow);
      float p2 = exp2a(sc[f][2] - mrow);
      float p3 = exp2a(sc[f][3] - mrow);
      sc[f][0] = p0; sc[f][1] = p1; sc[f][2] = p2; sc[f][3] = p3;
      ps0 += p0; ps1 += p1; ps2 += p2; ps3 += p3;
    }
    float ps = (ps0 + ps1) + (ps2 + ps3);
    ps += __shfl_xor(ps, 16);
    ps += __shfl_xor(ps, 32);
    lrow = lrow * alpha + ps;

    // P^T row (q=c0) -> per-wave LDS via cvt_pk (8 b32 writes)
    {
      char* pbrow = (char*)&pbuf[wid][0][0] + c0 * 176;
#pragma unroll
      for (int f = 0; f < 4; ++f) {
        unsigned int u0 = cvtpk(sc[f][0], sc[f][1]);
        unsigned int u1 = cvtpk(sc[f][2], sc[f][3]);
        *(unsigned int*)(pbrow + (f * 16 + gi * 4) * 2)     = u0;
        *(unsigned int*)(pbrow + (f * 16 + gi * 4) * 2 + 4) = u1;
      }
    }
    asm volatile("s_waitcnt lgkmcnt(0)" ::: "memory");

    // PV: O += P * V  (A-frag: row q=c0, kv-chunk ks*32+gi*8; unchanged layout)
    {
      const char* pb = (const char*)&pbuf[wid][0][0] + c0 * 176;
      const char* vcur = vbuf[tt & 1];
#pragma unroll
      for (int ks = 0; ks < 2; ++ks) {
        bf16x8 pa = *(const bf16x8*)(pb + ks * 64 + gi * 16);
#pragma unroll
        for (int df = 0; df < 4; ++df) {
          int rv = df * 16 + c0;
          int uL = ks * 4 + gi;
          bf16x8 vf = *(const bf16x8*)(vcur + rv * 128 + ((uL ^ (rv & 7)) * 16));
          o[df] = __builtin_amdgcn_mfma_f32_16x16x32_bf16(pa, vf, o[df], 0, 0, 0);
        }
      }
    }
  }

  // store UNNORMALIZED partial: O bf16 [64][64] (row q, col d), m/l per row
  unsigned short* po = pO + (size_t)pid * 4096;
#pragma unroll
  for (int i = 0; i < 4; ++i) {
    int r = wid * 16 + gi * 4 + i;
#pragma unroll
    for (int df = 0; df < 4; ++df)
      po[r * 64 + df * 16 + c0] = f2bf(o[df][i]);
  }
  if (lane < 16) {
    pm[pid * 64 + wid * 16 + c0] = mrow;
    pl[pid * 64 + wid * 16 + c0] = lrow;
  }
}

// ---------------- combine partials -> attn output [B*S, 1024] bf16 ----------
__global__ __launch_bounds__(256) void attn_combine(
    const unsigned short* __restrict__ pO,
    const float* __restrict__ pm,
    const float* __restrict__ pl,
    unsigned short* __restrict__ Out)
{
  int qt = blockIdx.x, bh = blockIdx.y;
  int t = threadIdx.x;
  int r = t >> 2, cseg = (t & 3) * 16;
  int pid0 = bh * 48 + qt;
  bool two = (qt >= 16);
  int pid1 = bh * 48 + 32 + qt - 16;

  float m0 = pm[pid0 * 64 + r];
  float l0 = pl[pid0 * 64 + r];
  float M = m0, w0 = 1.f, w1 = 0.f, l = l0;
  if (two) {
    float m1 = pm[pid1 * 64 + r];
    float l1 = pl[pid1 * 64 + r];
    M = fmaxf(m0, m1);
    w0 = exp2a(m0 - M);
    w1 = exp2a(m1 - M);
    l = w0 * l0 + w1 * l1;
  }
  float rl = 1.0f / l;

  const unsigned short* o0 = pO + (size_t)pid0 * 4096 + r * 64 + cseg;
  const unsigned short* o1 = pO + (size_t)pid1 * 4096 + r * 64 + cseg;
  int b = bh >> 4, h = bh & 15;
  size_t base = ((size_t)(b * S_LEN) + (qt * 64 + r)) * DM + h * DKH + cseg;

  bf16x8 a0 = *(const bf16x8*)o0;
  bf16x8 a1 = *(const bf16x8*)(o0 + 8);
  unsigned short res[16];
  if (two) {
    bf16x8 b0 = *(const bf16x8*)o1;
    bf16x8 b1 = *(const bf16x8*)(o1 + 8);
#pragma unroll
    for (int j = 0; j < 8; ++j) {
      res[j]     = f2bf((w0 * bf2f((unsigned short)a0[j]) + w1 * bf2f((unsigned short)b0[j])) * rl);
      res[j + 8] = f2bf((w0 * bf2f((unsigned short)a1[j]) + w1 * bf2f((unsigned short)b1[j])) * rl);
    }
  } else {
#pragma unroll
    for (int j = 0; j < 8; ++j) {
      res[j]     = f2bf(bf2f((unsigned short)a0[j]) * rl);
      res[j + 8] = f2bf(bf2f((unsigned short)a1[j]) * rl);
    }
  }
  *(u32x4*)(Out + base)     = *(u32x4*)res;
  *(u32x4*)(Out + base + 8) = *(u32x4*)(res + 8);
}

// ----------------------------------------------------------------------------
extern "C" void kernel_launch(void* const* d_in, const int* in_sizes, int n_in,
                              void* d_out, int out_size, void* d_ws, size_t ws_size,
                              hipStream_t stream) {
  const float* x       = (const float*)d_in[0];
  const float* w_atten = (const float*)d_in[1];
  const float* b_atten = (const float*)d_in[2];
  const float* w_proj  = (const float*)d_in[3];
  const float* b_proj  = (const float*)d_in[4];
  float* out = (float*)d_out;
  char* ws = (char*)d_ws;

  unsigned short* x_bf  = (unsigned short*)(ws);
  unsigned short* wa_bf = (unsigned short*)(ws + ((size_t)8  << 20));
  unsigned short* wp_bf = (unsigned short*)(ws + ((size_t)14 << 20));
  unsigned short* q_bf  = (unsigned short*)(ws + ((size_t)16 << 20));
  unsigned short* k_bf  = (unsigned short*)(ws + ((size_t)24 << 20));
  unsigned short* vt_bf = (unsigned short*)(ws + ((size_t)32 << 20));
  unsigned short* at_bf = (unsigned short*)(ws + ((size_t)40 << 20));
  // partial buffers overlay x_bf/wa_bf (dead after gemm0)
  unsigned short* pO = (unsigned short*)(ws);
  float* pm = (float*)(ws + 12582912);
  float* pl = (float*)(ws + 12976128);

  cvt_f32_to_bf16<<<2048, 256, 0, stream>>>(x, x_bf, 4194304);
  cvt_f32_to_bf16<<<1536, 256, 0, stream>>>(w_atten, wa_bf, 3145728);
  cvt_f32_to_bf16<<<512, 256, 0, stream>>>(w_proj, wp_bf, 1048576);

  gemm_bt<0><<<dim3(24, 32), 256, 0, stream>>>(x_bf, wa_bf, b_atten, nullptr,
                                               q_bf, k_bf, vt_bf, 4096, 3072, 1024);
  attn_part<<<dim3(48, 32), 256, 0, stream>>>(q_bf, k_bf, vt_bf, pO, pm, pl);
  attn_combine<<<dim3(32, 32), 256, 0, stream>>>(pO, pm, pl, at_bf);
  gemm_bt<1><<<dim3(8, 32), 256, 0, stream>>>(at_bf, wp_bf, b_proj, out,
                                              nullptr, nullptr, nullptr, 4096, 1024, 1024);
}